// Round 1
// baseline (1309.246 us; speedup 1.0000x reference)
//
#include <hip/hip_runtime.h>
#include <hip/hip_bf16.h>
#include <stdint.h>

// DeepseekCompressor: out_cache = scatter(slot_mapping,
//     concat([x@W[:512]^T, x@W[512:]^T + ape[pos%128]], -1)) over copy(state_cache)
//
// GEMM: M=16384 (tokens), N=1024 (2*D), K=7168 (hidden), fp32 in -> bf16 MFMA.
// Structure: m93/m97 ladder — 128x128 block tile, 256 thr = 4 waves (2x2),
// each wave 64x64 = 4x4 frags of v_mfma_f32_16x16x32_bf16. fp32->bf16 RNE
// convert fused into LDS staging. XOR-swizzled LDS (16B chunks) for
// conflict-free ds_read_b128 fragment loads.

typedef short  bf16x8 __attribute__((ext_vector_type(8)));   // 8 bf16 bit-patterns (4 VGPRs)
typedef float  f32x4  __attribute__((ext_vector_type(4)));

#define BM 128
#define BN 128
#define BK 32
#define NTHREADS 256

__device__ __forceinline__ uint32_t pack_bf16x2(float lo, float hi) {
    // round-to-nearest-even fp32 -> bf16, pack (hi<<16)|lo
    uint32_t a = __float_as_uint(lo);
    uint32_t b = __float_as_uint(hi);
    a += 0x7fffu + ((a >> 16) & 1u);
    b += 0x7fffu + ((b >> 16) & 1u);
    return (a >> 16) | (b & 0xffff0000u);
}

// swizzled ushort index for (row, 16B-chunk): 4 chunks per 32-elem row
__device__ __forceinline__ int lds_idx(int row, int chunk) {
    return row * BK + ((chunk ^ ((row >> 1) & 3)) << 3);
}

__global__ __launch_bounds__(NTHREADS, 2)
void gemm_scatter(const float* __restrict__ X, const float* __restrict__ Wm,
                  const float* __restrict__ ape, const int* __restrict__ positions,
                  const int* __restrict__ slots, float* __restrict__ out,
                  int K, int D, int CR, int num_slots, int n_tiles_n)
{
    __shared__ uint16_t ldsA[BM * BK];
    __shared__ uint16_t ldsB[BN * BK];

    const int tile_m = blockIdx.x / n_tiles_n;   // m-major: n-tiles of one m-strip adjacent -> L2 reuse of x
    const int tile_n = blockIdx.x % n_tiles_n;
    const int t    = threadIdx.x;
    const int lane = t & 63;
    const int wid  = t >> 6;
    const int wm   = (wid >> 1) * 64;
    const int wn   = (wid & 1) * 64;
    const int fr   = lane & 15;   // fragment row index (A: m, B: n)
    const int fc   = lane >> 4;   // k-chunk 0..3
    const int swz  = fc ^ ((fr >> 1) & 3);

    const float* Abase = X  + (size_t)(tile_m * BM) * K;
    const float* Bbase = Wm + (size_t)(tile_n * BN) * K;

    f32x4 acc[4][4];
    #pragma unroll
    for (int i = 0; i < 4; i++)
        #pragma unroll
        for (int j = 0; j < 4; j++)
            acc[i][j] = f32x4{0.f, 0.f, 0.f, 0.f};

    for (int k0 = 0; k0 < K; k0 += BK) {
        // ---- stage 128x32 fp32 of A and B -> bf16 LDS (swizzled) ----
        #pragma unroll
        for (int i = 0; i < 4; i++) {
            const int lin = t + i * NTHREADS;   // 0..1023
            const int row = lin >> 3;           // 0..127
            const int c4  = lin & 7;            // float4 column
            const int half = c4 & 1;
            const int sidx = lds_idx(row, c4 >> 1) + half * 4;

            const float4 va = *(const float4*)(Abase + (size_t)row * K + k0 + c4 * 4);
            uint2 pa;
            pa.x = pack_bf16x2(va.x, va.y);
            pa.y = pack_bf16x2(va.z, va.w);
            *(uint2*)&ldsA[sidx] = pa;

            const float4 vb = *(const float4*)(Bbase + (size_t)row * K + k0 + c4 * 4);
            uint2 pb;
            pb.x = pack_bf16x2(vb.x, vb.y);
            pb.y = pack_bf16x2(vb.z, vb.w);
            *(uint2*)&ldsB[sidx] = pb;
        }
        __syncthreads();

        // ---- fragments + MFMA ----
        bf16x8 af[4], bfrag[4];
        #pragma unroll
        for (int i = 0; i < 4; i++)
            af[i] = *(const bf16x8*)&ldsA[(wm + i * 16 + fr) * BK + (swz << 3)];
        #pragma unroll
        for (int j = 0; j < 4; j++)
            bfrag[j] = *(const bf16x8*)&ldsB[(wn + j * 16 + fr) * BK + (swz << 3)];

        #pragma unroll
        for (int i = 0; i < 4; i++)
            #pragma unroll
            for (int j = 0; j < 4; j++)
                acc[i][j] = __builtin_amdgcn_mfma_f32_16x16x32_bf16(af[i], bfrag[j], acc[i][j], 0, 0, 0);
        __syncthreads();
    }

    // ---- epilogue: C/D layout col=lane&15, row=(lane>>4)*4+reg ----
    const int D2 = 2 * D;
    #pragma unroll
    for (int i = 0; i < 4; i++) {
        #pragma unroll
        for (int r = 0; r < 4; r++) {
            const int token = tile_m * BM + wm + i * 16 + fc * 4 + r;
            const int slot  = slots[token];
            if (slot < 0 || slot >= num_slots) continue;
            const int p = positions[token] % CR;
            const float* aperow = ape + (size_t)p * D;
            float* orow = out + (size_t)slot * D2;
            #pragma unroll
            for (int j = 0; j < 4; j++) {
                const int col = tile_n * BN + wn + j * 16 + fr;
                float v = acc[i][j][r];
                if (col >= D) v += aperow[col - D];   // uniform across 16 lanes (no divergence)
                orow[col] = v;
            }
        }
    }
}

__global__ void copy_cache(const float4* __restrict__ src, float4* __restrict__ dst, int n4) {
    const int i = blockIdx.x * blockDim.x + threadIdx.x;
    if (i < n4) dst[i] = src[i];
}

extern "C" void kernel_launch(void* const* d_in, const int* in_sizes, int n_in,
                              void* d_out, int out_size, void* d_ws, size_t ws_size,
                              hipStream_t stream) {
    const float* x         = (const float*)d_in[0];
    const float* W         = (const float*)d_in[1];
    const float* ape       = (const float*)d_in[2];
    const float* cache     = (const float*)d_in[3];
    const int*   positions = (const int*)d_in[4];
    const int*   slots     = (const int*)d_in[5];
    float* out = (float*)d_out;

    const int num_tokens = in_sizes[4];
    const int hidden     = in_sizes[0] / num_tokens;   // 7168
    const int D2         = in_sizes[1] / hidden;       // 1024
    const int D          = D2 / 2;                     // 512
    const int CR         = in_sizes[2] / D;            // 128
    const int num_slots  = in_sizes[3] / D2;           // 32768

    // 1) passthrough copy of the whole cache (untouched rows must survive)
    const int n4 = out_size / 4;
    copy_cache<<<(n4 + 255) / 256, 256, 0, stream>>>((const float4*)cache, (float4*)out, n4);

    // 2) GEMM + ape-add + scatter (overwrites mapped rows)
    const int n_tiles_m = num_tokens / BM;   // 128
    const int n_tiles_n = D2 / BN;           // 8
    gemm_scatter<<<n_tiles_m * n_tiles_n, NTHREADS, 0, stream>>>(
        x, W, ape, positions, slots, out, hidden, D, CR, num_slots, n_tiles_n);
}

// Round 2
// 1114.511 us; speedup vs baseline: 1.1747x; 1.1747x over previous
//
#include <hip/hip_runtime.h>
#include <hip/hip_bf16.h>
#include <stdint.h>

// DeepseekCompressor: out = scatter(slots, [x@W0^T, x@W1^T + ape[pos%128]]) over copy(cache)
// Round 2: pre-convert x,W -> bf16 in d_ws (memory-bound pass), then m97-style
// GEMM: global_load_lds width=16 staging (XOR-swizzled on the global-source side,
// since LDS dest is lane-linear), 128x128 tile, 4 waves 2x2, 4x4 frags of
// v_mfma_f32_16x16x32_bf16. Fallback to round-1 fp32-staging kernel if ws too small.

typedef short  bf16x8 __attribute__((ext_vector_type(8)));
typedef float  f32x4  __attribute__((ext_vector_type(4)));

#define BM 128
#define BN 128
#define BK 32
#define NT 256

__device__ __forceinline__ uint32_t pack_bf16x2(float lo, float hi) {
    uint32_t a = __float_as_uint(lo);
    uint32_t b = __float_as_uint(hi);
    a += 0x7fffu + ((a >> 16) & 1u);
    b += 0x7fffu + ((b >> 16) & 1u);
    return (a >> 16) | (b & 0xffff0000u);
}

__device__ __forceinline__ void gload_lds16(const uint16_t* g, uint16_t* l) {
    __builtin_amdgcn_global_load_lds(
        (const __attribute__((address_space(1))) uint32_t*)g,
        (__attribute__((address_space(3))) uint32_t*)l,
        16, 0, 0);
}

// ---------------- fp32 -> bf16 convert pass (grid-stride, 8 elems/thread/step) ----
__global__ void cvt_bf16(const float4* __restrict__ src, uint4* __restrict__ dst, int n8) {
    int i = blockIdx.x * blockDim.x + threadIdx.x;
    const int stride = gridDim.x * blockDim.x;
    for (; i < n8; i += stride) {
        const float4 a = src[2 * i];
        const float4 b = src[2 * i + 1];
        uint4 o;
        o.x = pack_bf16x2(a.x, a.y);
        o.y = pack_bf16x2(a.z, a.w);
        o.z = pack_bf16x2(b.x, b.y);
        o.w = pack_bf16x2(b.z, b.w);
        dst[i] = o;
    }
}

// ---------------- cache passthrough copy ----------------
__global__ void copy_cache(const float4* __restrict__ src, float4* __restrict__ dst, int n4) {
    const int i = blockIdx.x * blockDim.x + threadIdx.x;
    if (i < n4) dst[i] = src[i];
}

// ---------------- m97-style bf16 GEMM + ape + scatter ----------------
__global__ __launch_bounds__(NT, 4)
void gemm_bf16_scatter(const uint16_t* __restrict__ XB, const uint16_t* __restrict__ WB,
                       const float* __restrict__ ape, const int* __restrict__ positions,
                       const int* __restrict__ slots, float* __restrict__ out,
                       int K, int D, int CR, int num_slots, int n_tiles_n)
{
    __shared__ uint16_t ldsA[BM * BK];   // 8 KB, rows of 32 bf16 = 4x16B chunks, chunk c of row r stored at c^(r&3)
    __shared__ uint16_t ldsB[BN * BK];   // 8 KB

    const int tile_m = blockIdx.x / n_tiles_n;   // m-major: 8 n-tiles sharing an x-strip are adjacent
    const int tile_n = blockIdx.x % n_tiles_n;
    const int t    = threadIdx.x;
    const int lane = t & 63;
    const int wid  = t >> 6;
    const int wm   = (wid >> 1) * 64;
    const int wn   = (wid & 1) * 64;
    const int fr   = lane & 15;
    const int fc   = lane >> 4;
    const int swz  = (fc ^ (fr & 3)) << 3;       // element offset of the swizzled 16B chunk

    // staging: 512 16B-chunks per matrix per k-iter; 2 issues x 256 threads.
    // LDS position p = t + it*256 holds global chunk (r = p>>2, csrc = (p&3)^(r&3)).
    const int p0 = t, p1 = t + NT;
    const int r0 = p0 >> 2, c0 = (p0 & 3) ^ (r0 & 3);
    const int r1 = p1 >> 2, c1 = (p1 & 3) ^ (r1 & 3);

    const uint16_t* gA0 = XB + (size_t)(tile_m * BM + r0) * K + c0 * 8;
    const uint16_t* gA1 = XB + (size_t)(tile_m * BM + r1) * K + c1 * 8;
    const uint16_t* gB0 = WB + (size_t)(tile_n * BN + r0) * K + c0 * 8;
    const uint16_t* gB1 = WB + (size_t)(tile_n * BN + r1) * K + c1 * 8;
    uint16_t* lA0 = &ldsA[p0 * 8];
    uint16_t* lA1 = &ldsA[p1 * 8];
    uint16_t* lB0 = &ldsB[p0 * 8];
    uint16_t* lB1 = &ldsB[p1 * 8];

    f32x4 acc[4][4];
    #pragma unroll
    for (int i = 0; i < 4; i++)
        #pragma unroll
        for (int j = 0; j < 4; j++)
            acc[i][j] = f32x4{0.f, 0.f, 0.f, 0.f};

    for (int k0 = 0; k0 < K; k0 += BK) {
        gload_lds16(gA0 + k0, lA0);
        gload_lds16(gA1 + k0, lA1);
        gload_lds16(gB0 + k0, lB0);
        gload_lds16(gB1 + k0, lB1);
        __syncthreads();   // drains vmcnt -> LDS staging visible

        bf16x8 af[4], bfrag[4];
        #pragma unroll
        for (int i = 0; i < 4; i++)
            af[i] = *(const bf16x8*)&ldsA[(wm + i * 16 + fr) * BK + swz];
        #pragma unroll
        for (int j = 0; j < 4; j++)
            bfrag[j] = *(const bf16x8*)&ldsB[(wn + j * 16 + fr) * BK + swz];

        #pragma unroll
        for (int i = 0; i < 4; i++)
            #pragma unroll
            for (int j = 0; j < 4; j++)
                acc[i][j] = __builtin_amdgcn_mfma_f32_16x16x32_bf16(af[i], bfrag[j], acc[i][j], 0, 0, 0);
        __syncthreads();   // LDS safe to overwrite
    }

    // epilogue: C/D layout col=lane&15, row=(lane>>4)*4+reg (m89-verified)
    const int D2 = 2 * D;
    #pragma unroll
    for (int i = 0; i < 4; i++) {
        #pragma unroll
        for (int r = 0; r < 4; r++) {
            const int token = tile_m * BM + wm + i * 16 + fc * 4 + r;
            const int slot  = slots[token];
            if (slot < 0 || slot >= num_slots) continue;
            const int p = positions[token] % CR;
            const float* aperow = ape + (size_t)p * D;
            float* orow = out + (size_t)slot * D2;
            #pragma unroll
            for (int j = 0; j < 4; j++) {
                const int col = tile_n * BN + wn + j * 16 + fr;
                float v = acc[i][j][r];
                if (col >= D) v += aperow[col - D];
                orow[col] = v;
            }
        }
    }
}

// ---------------- fallback: round-1 fp32-staging GEMM (used only if ws too small) ----
__device__ __forceinline__ int lds_idx_f(int row, int chunk) {
    return row * BK + ((chunk ^ ((row >> 1) & 3)) << 3);
}

__global__ __launch_bounds__(NT, 2)
void gemm_scatter_f32(const float* __restrict__ X, const float* __restrict__ Wm,
                      const float* __restrict__ ape, const int* __restrict__ positions,
                      const int* __restrict__ slots, float* __restrict__ out,
                      int K, int D, int CR, int num_slots, int n_tiles_n)
{
    __shared__ uint16_t ldsA[BM * BK];
    __shared__ uint16_t ldsB[BN * BK];

    const int tile_m = blockIdx.x / n_tiles_n;
    const int tile_n = blockIdx.x % n_tiles_n;
    const int t    = threadIdx.x;
    const int lane = t & 63;
    const int wid  = t >> 6;
    const int wm   = (wid >> 1) * 64;
    const int wn   = (wid & 1) * 64;
    const int fr   = lane & 15;
    const int fc   = lane >> 4;
    const int swz  = fc ^ ((fr >> 1) & 3);

    const float* Abase = X  + (size_t)(tile_m * BM) * K;
    const float* Bbase = Wm + (size_t)(tile_n * BN) * K;

    f32x4 acc[4][4];
    #pragma unroll
    for (int i = 0; i < 4; i++)
        #pragma unroll
        for (int j = 0; j < 4; j++)
            acc[i][j] = f32x4{0.f, 0.f, 0.f, 0.f};

    for (int k0 = 0; k0 < K; k0 += BK) {
        #pragma unroll
        for (int i = 0; i < 4; i++) {
            const int lin = t + i * NT;
            const int row = lin >> 3;
            const int c4  = lin & 7;
            const int half = c4 & 1;
            const int sidx = lds_idx_f(row, c4 >> 1) + half * 4;

            const float4 va = *(const float4*)(Abase + (size_t)row * K + k0 + c4 * 4);
            uint2 pa; pa.x = pack_bf16x2(va.x, va.y); pa.y = pack_bf16x2(va.z, va.w);
            *(uint2*)&ldsA[sidx] = pa;

            const float4 vb = *(const float4*)(Bbase + (size_t)row * K + k0 + c4 * 4);
            uint2 pb; pb.x = pack_bf16x2(vb.x, vb.y); pb.y = pack_bf16x2(vb.z, vb.w);
            *(uint2*)&ldsB[sidx] = pb;
        }
        __syncthreads();

        bf16x8 af[4], bfrag[4];
        #pragma unroll
        for (int i = 0; i < 4; i++)
            af[i] = *(const bf16x8*)&ldsA[(wm + i * 16 + fr) * BK + (swz << 3)];
        #pragma unroll
        for (int j = 0; j < 4; j++)
            bfrag[j] = *(const bf16x8*)&ldsB[(wn + j * 16 + fr) * BK + (swz << 3)];

        #pragma unroll
        for (int i = 0; i < 4; i++)
            #pragma unroll
            for (int j = 0; j < 4; j++)
                acc[i][j] = __builtin_amdgcn_mfma_f32_16x16x32_bf16(af[i], bfrag[j], acc[i][j], 0, 0, 0);
        __syncthreads();
    }

    const int D2 = 2 * D;
    #pragma unroll
    for (int i = 0; i < 4; i++) {
        #pragma unroll
        for (int r = 0; r < 4; r++) {
            const int token = tile_m * BM + wm + i * 16 + fc * 4 + r;
            const int slot  = slots[token];
            if (slot < 0 || slot >= num_slots) continue;
            const int p = positions[token] % CR;
            const float* aperow = ape + (size_t)p * D;
            float* orow = out + (size_t)slot * D2;
            #pragma unroll
            for (int j = 0; j < 4; j++) {
                const int col = tile_n * BN + wn + j * 16 + fr;
                float v = acc[i][j][r];
                if (col >= D) v += aperow[col - D];
                orow[col] = v;
            }
        }
    }
}

extern "C" void kernel_launch(void* const* d_in, const int* in_sizes, int n_in,
                              void* d_out, int out_size, void* d_ws, size_t ws_size,
                              hipStream_t stream) {
    const float* x         = (const float*)d_in[0];
    const float* W         = (const float*)d_in[1];
    const float* ape       = (const float*)d_in[2];
    const float* cache     = (const float*)d_in[3];
    const int*   positions = (const int*)d_in[4];
    const int*   slots     = (const int*)d_in[5];
    float* out = (float*)d_out;

    const int num_tokens = in_sizes[4];
    const int hidden     = in_sizes[0] / num_tokens;   // 7168
    const int D2         = in_sizes[1] / hidden;       // 1024
    const int D          = D2 / 2;                     // 512
    const int CR         = in_sizes[2] / D;            // 128
    const int num_slots  = in_sizes[3] / D2;           // 32768

    const int n4 = out_size / 4;
    copy_cache<<<(n4 + 255) / 256, 256, 0, stream>>>((const float4*)cache, (float4*)out, n4);

    const int n_tiles_m = num_tokens / BM;   // 128
    const int n_tiles_n = D2 / BN;           // 8

    const size_t nx = (size_t)in_sizes[0];
    const size_t nw = (size_t)in_sizes[1];
    const size_t need = (nx + nw) * sizeof(uint16_t);

    if (ws_size >= need) {
        uint16_t* xb = (uint16_t*)d_ws;
        uint16_t* wb = xb + nx;
        cvt_bf16<<<4096, 256, 0, stream>>>((const float4*)x, (uint4*)xb, (int)(nx / 8));
        cvt_bf16<<<1024, 256, 0, stream>>>((const float4*)W, (uint4*)wb, (int)(nw / 8));
        gemm_bf16_scatter<<<n_tiles_m * n_tiles_n, NT, 0, stream>>>(
            xb, wb, ape, positions, slots, out, hidden, D, CR, num_slots, n_tiles_n);
    } else {
        gemm_scatter_f32<<<n_tiles_m * n_tiles_n, NT, 0, stream>>>(
            x, W, ape, positions, slots, out, hidden, D, CR, num_slots, n_tiles_n);
    }
}

// Round 3
// 1047.189 us; speedup vs baseline: 1.2502x; 1.0643x over previous
//
#include <hip/hip_runtime.h>
#include <hip/hip_bf16.h>
#include <stdint.h>

// DeepseekCompressor: out = scatter(slots, [x@W0^T, x@W1^T + ape[pos%128]]) over copy(cache)
// Round 3 changes vs round 2:
//  - LDS swizzle reverted to conflict-free variant: chunk = fc ^ ((row>>1)&3)
//    (round 1 measured 0 conflicts; round 2's fc^(row&3) measured 2.9e7 = 4-way).
//    global_load_lds source address carries the swizzle; LDS dest stays lane-linear.
//  - n-major block order (tile_m = bid % n_tiles_m): the 8 blocks sharing an
//    x-strip are == mod 8 -> same XCD under round-robin dispatch -> x fetched once.
//  - copy+cvt_x+cvt_w fused into one grid-stride "prep" kernel; cache rows that
//    the scatter will overwrite are skipped via a flag array in d_ws.

typedef short  bf16x8 __attribute__((ext_vector_type(8)));
typedef float  f32x4  __attribute__((ext_vector_type(4)));

#define BM 128
#define BN 128
#define BK 32
#define NT 256

__device__ __forceinline__ uint32_t pack_bf16x2(float lo, float hi) {
    uint32_t a = __float_as_uint(lo);
    uint32_t b = __float_as_uint(hi);
    a += 0x7fffu + ((a >> 16) & 1u);
    b += 0x7fffu + ((b >> 16) & 1u);
    return (a >> 16) | (b & 0xffff0000u);
}

__device__ __forceinline__ void gload_lds16(const uint16_t* g, uint16_t* l) {
    __builtin_amdgcn_global_load_lds(
        (const __attribute__((address_space(1))) uint32_t*)g,
        (__attribute__((address_space(3))) uint32_t*)l,
        16, 0, 0);
}

// ---------------- flag mapped slots ----------------
__global__ void set_flags(const int* __restrict__ slots, uint8_t* __restrict__ flags,
                          int num_tokens, int num_slots) {
    const int i = blockIdx.x * blockDim.x + threadIdx.x;
    if (i < num_tokens) {
        const int s = slots[i];
        if (s >= 0 && s < num_slots) flags[s] = 1;
    }
}

// ---------------- fused prep: cache copy (skip overwritten) + cvt x + cvt W ----
__global__ void prep(const float4* __restrict__ cache, float4* __restrict__ out,
                     const uint8_t* __restrict__ flags,
                     const float4* __restrict__ x, uint4* __restrict__ xb,
                     const float4* __restrict__ w, uint4* __restrict__ wb,
                     int n_c4, int nx8, int nw8) {
    const int i = blockIdx.x * blockDim.x + threadIdx.x;
    if (i < n_c4) {
        // cache row = 1024 floats = 256 float4
        if (!flags[i >> 8]) out[i] = cache[i];
    } else if (i < n_c4 + nx8) {
        const int j = i - n_c4;
        const float4 a = x[2 * j];
        const float4 b = x[2 * j + 1];
        uint4 o;
        o.x = pack_bf16x2(a.x, a.y);
        o.y = pack_bf16x2(a.z, a.w);
        o.z = pack_bf16x2(b.x, b.y);
        o.w = pack_bf16x2(b.z, b.w);
        xb[j] = o;
    } else if (i < n_c4 + nx8 + nw8) {
        const int j = i - n_c4 - nx8;
        const float4 a = w[2 * j];
        const float4 b = w[2 * j + 1];
        uint4 o;
        o.x = pack_bf16x2(a.x, a.y);
        o.y = pack_bf16x2(a.z, a.w);
        o.z = pack_bf16x2(b.x, b.y);
        o.w = pack_bf16x2(b.z, b.w);
        wb[j] = o;
    }
}

// ---------------- m97-style bf16 GEMM + ape + scatter ----------------
__global__ __launch_bounds__(NT, 4)
void gemm_bf16_scatter(const uint16_t* __restrict__ XB, const uint16_t* __restrict__ WB,
                       const float* __restrict__ ape, const int* __restrict__ positions,
                       const int* __restrict__ slots, float* __restrict__ out,
                       int K, int D, int CR, int num_slots, int n_tiles_m)
{
    __shared__ uint16_t ldsA[BM * BK];   // 8 KB: LDS[r][cl] = G[r][cl ^ ((r>>1)&3)], 16B chunks
    __shared__ uint16_t ldsB[BN * BK];   // 8 KB

    // n-major: x-strip sharers are bid ≡ same (mod 8) -> same XCD (round-robin heuristic)
    const int tile_m = blockIdx.x % n_tiles_m;
    const int tile_n = blockIdx.x / n_tiles_m;
    const int t    = threadIdx.x;
    const int lane = t & 63;
    const int wid  = t >> 6;
    const int wm   = (wid >> 1) * 64;
    const int wn   = (wid & 1) * 64;
    const int fr   = lane & 15;
    const int fc   = lane >> 4;
    const int swz  = (fc ^ ((fr >> 1) & 3)) << 3;   // conflict-free: 2-way max (m136: free)

    // staging: 512 16B-chunks per matrix per k-iter; LDS position p holds
    // global chunk (r = p>>2, csrc = (p&3) ^ ((r>>1)&3)).
    const int p0 = t, p1 = t + NT;
    const int r0 = p0 >> 2, c0 = (p0 & 3) ^ ((r0 >> 1) & 3);
    const int r1 = p1 >> 2, c1 = (p1 & 3) ^ ((r1 >> 1) & 3);

    const uint16_t* gA0 = XB + (size_t)(tile_m * BM + r0) * K + c0 * 8;
    const uint16_t* gA1 = XB + (size_t)(tile_m * BM + r1) * K + c1 * 8;
    const uint16_t* gB0 = WB + (size_t)(tile_n * BN + r0) * K + c0 * 8;
    const uint16_t* gB1 = WB + (size_t)(tile_n * BN + r1) * K + c1 * 8;
    uint16_t* lA0 = &ldsA[p0 * 8];
    uint16_t* lA1 = &ldsA[p1 * 8];
    uint16_t* lB0 = &ldsB[p0 * 8];
    uint16_t* lB1 = &ldsB[p1 * 8];

    f32x4 acc[4][4];
    #pragma unroll
    for (int i = 0; i < 4; i++)
        #pragma unroll
        for (int j = 0; j < 4; j++)
            acc[i][j] = f32x4{0.f, 0.f, 0.f, 0.f};

    for (int k0 = 0; k0 < K; k0 += BK) {
        gload_lds16(gA0 + k0, lA0);
        gload_lds16(gA1 + k0, lA1);
        gload_lds16(gB0 + k0, lB0);
        gload_lds16(gB1 + k0, lB1);
        __syncthreads();

        bf16x8 af[4], bfrag[4];
        #pragma unroll
        for (int i = 0; i < 4; i++)
            af[i] = *(const bf16x8*)&ldsA[(wm + i * 16 + fr) * BK + swz];
        #pragma unroll
        for (int j = 0; j < 4; j++)
            bfrag[j] = *(const bf16x8*)&ldsB[(wn + j * 16 + fr) * BK + swz];

        #pragma unroll
        for (int i = 0; i < 4; i++)
            #pragma unroll
            for (int j = 0; j < 4; j++)
                acc[i][j] = __builtin_amdgcn_mfma_f32_16x16x32_bf16(af[i], bfrag[j], acc[i][j], 0, 0, 0);
        __syncthreads();
    }

    // epilogue: C/D layout col=lane&15, row=(lane>>4)*4+reg (m89-verified)
    const int D2 = 2 * D;
    #pragma unroll
    for (int i = 0; i < 4; i++) {
        #pragma unroll
        for (int r = 0; r < 4; r++) {
            const int token = tile_m * BM + wm + i * 16 + fc * 4 + r;
            const int slot  = slots[token];
            if (slot < 0 || slot >= num_slots) continue;
            const int p = positions[token] % CR;
            const float* aperow = ape + (size_t)p * D;
            float* orow = out + (size_t)slot * D2;
            #pragma unroll
            for (int j = 0; j < 4; j++) {
                const int col = tile_n * BN + wn + j * 16 + fr;
                float v = acc[i][j][r];
                if (col >= D) v += aperow[col - D];
                orow[col] = v;
            }
        }
    }
}

// ---------------- fallback (ws too small): round-1 fp32-staging GEMM ----------------
__global__ void copy_cache(const float4* __restrict__ src, float4* __restrict__ dst, int n4) {
    const int i = blockIdx.x * blockDim.x + threadIdx.x;
    if (i < n4) dst[i] = src[i];
}

__device__ __forceinline__ int lds_idx_f(int row, int chunk) {
    return row * BK + ((chunk ^ ((row >> 1) & 3)) << 3);
}

__global__ __launch_bounds__(NT, 2)
void gemm_scatter_f32(const float* __restrict__ X, const float* __restrict__ Wm,
                      const float* __restrict__ ape, const int* __restrict__ positions,
                      const int* __restrict__ slots, float* __restrict__ out,
                      int K, int D, int CR, int num_slots, int n_tiles_n)
{
    __shared__ uint16_t ldsA[BM * BK];
    __shared__ uint16_t ldsB[BN * BK];

    const int tile_m = blockIdx.x / n_tiles_n;
    const int tile_n = blockIdx.x % n_tiles_n;
    const int t    = threadIdx.x;
    const int lane = t & 63;
    const int wid  = t >> 6;
    const int wm   = (wid >> 1) * 64;
    const int wn   = (wid & 1) * 64;
    const int fr   = lane & 15;
    const int fc   = lane >> 4;
    const int swz  = fc ^ ((fr >> 1) & 3);

    const float* Abase = X  + (size_t)(tile_m * BM) * K;
    const float* Bbase = Wm + (size_t)(tile_n * BN) * K;

    f32x4 acc[4][4];
    #pragma unroll
    for (int i = 0; i < 4; i++)
        #pragma unroll
        for (int j = 0; j < 4; j++)
            acc[i][j] = f32x4{0.f, 0.f, 0.f, 0.f};

    for (int k0 = 0; k0 < K; k0 += BK) {
        #pragma unroll
        for (int i = 0; i < 4; i++) {
            const int lin = t + i * NT;
            const int row = lin >> 3;
            const int c4  = lin & 7;
            const int half = c4 & 1;
            const int sidx = lds_idx_f(row, c4 >> 1) + half * 4;

            const float4 va = *(const float4*)(Abase + (size_t)row * K + k0 + c4 * 4);
            uint2 pa; pa.x = pack_bf16x2(va.x, va.y); pa.y = pack_bf16x2(va.z, va.w);
            *(uint2*)&ldsA[sidx] = pa;

            const float4 vb = *(const float4*)(Bbase + (size_t)row * K + k0 + c4 * 4);
            uint2 pb; pb.x = pack_bf16x2(vb.x, vb.y); pb.y = pack_bf16x2(vb.z, vb.w);
            *(uint2*)&ldsB[sidx] = pb;
        }
        __syncthreads();

        bf16x8 af[4], bfrag[4];
        #pragma unroll
        for (int i = 0; i < 4; i++)
            af[i] = *(const bf16x8*)&ldsA[(wm + i * 16 + fr) * BK + (swz << 3)];
        #pragma unroll
        for (int j = 0; j < 4; j++)
            bfrag[j] = *(const bf16x8*)&ldsB[(wn + j * 16 + fr) * BK + (swz << 3)];

        #pragma unroll
        for (int i = 0; i < 4; i++)
            #pragma unroll
            for (int j = 0; j < 4; j++)
                acc[i][j] = __builtin_amdgcn_mfma_f32_16x16x32_bf16(af[i], bfrag[j], acc[i][j], 0, 0, 0);
        __syncthreads();
    }

    const int D2 = 2 * D;
    #pragma unroll
    for (int i = 0; i < 4; i++) {
        #pragma unroll
        for (int r = 0; r < 4; r++) {
            const int token = tile_m * BM + wm + i * 16 + fc * 4 + r;
            const int slot  = slots[token];
            if (slot < 0 || slot >= num_slots) continue;
            const int p = positions[token] % CR;
            const float* aperow = ape + (size_t)p * D;
            float* orow = out + (size_t)slot * D2;
            #pragma unroll
            for (int j = 0; j < 4; j++) {
                const int col = tile_n * BN + wn + j * 16 + fr;
                float v = acc[i][j][r];
                if (col >= D) v += aperow[col - D];
                orow[col] = v;
            }
        }
    }
}

extern "C" void kernel_launch(void* const* d_in, const int* in_sizes, int n_in,
                              void* d_out, int out_size, void* d_ws, size_t ws_size,
                              hipStream_t stream) {
    const float* x         = (const float*)d_in[0];
    const float* W         = (const float*)d_in[1];
    const float* ape       = (const float*)d_in[2];
    const float* cache     = (const float*)d_in[3];
    const int*   positions = (const int*)d_in[4];
    const int*   slots     = (const int*)d_in[5];
    float* out = (float*)d_out;

    const int num_tokens = in_sizes[4];
    const int hidden     = in_sizes[0] / num_tokens;   // 7168
    const int D2         = in_sizes[1] / hidden;       // 1024
    const int D          = D2 / 2;                     // 512
    const int CR         = in_sizes[2] / D;            // 128
    const int num_slots  = in_sizes[3] / D2;           // 32768

    const int n_tiles_m = num_tokens / BM;   // 128
    const int n_tiles_n = D2 / BN;           // 8

    const size_t nx = (size_t)in_sizes[0];
    const size_t nw = (size_t)in_sizes[1];
    const size_t need = (nx + nw) * sizeof(uint16_t) + (size_t)num_slots;

    if (ws_size >= need) {
        uint16_t* xb = (uint16_t*)d_ws;
        uint16_t* wb = xb + nx;
        uint8_t* flags = (uint8_t*)(wb + nw);

        hipMemsetAsync(flags, 0, num_slots, stream);
        set_flags<<<(num_tokens + 255) / 256, 256, 0, stream>>>(slots, flags, num_tokens, num_slots);

        const int n_c4 = out_size / 4;
        const int nx8  = (int)(nx / 8);
        const int nw8  = (int)(nw / 8);
        const int total = n_c4 + nx8 + nw8;
        prep<<<(total + 255) / 256, 256, 0, stream>>>(
            (const float4*)cache, (float4*)out, flags,
            (const float4*)x, (uint4*)xb, (const float4*)W, (uint4*)wb,
            n_c4, nx8, nw8);

        gemm_bf16_scatter<<<n_tiles_m * n_tiles_n, NT, 0, stream>>>(
            xb, wb, ape, positions, slots, out, hidden, D, CR, num_slots, n_tiles_m);
    } else {
        const int n4 = out_size / 4;
        copy_cache<<<(n4 + 255) / 256, 256, 0, stream>>>((const float4*)cache, (float4*)out, n4);
        gemm_scatter_f32<<<n_tiles_m * n_tiles_n, NT, 0, stream>>>(
            x, W, ape, positions, slots, out, hidden, D, CR, num_slots, n_tiles_n);
    }
}